// Round 25
// baseline (1362.529 us; speedup 1.0000x reference)
//
#include <hip/hip_runtime.h>
#include <hip/hip_bf16.h>

// WindowAttention (Swin) on MI355X — round 25
//   Base = R23/24 (859us). Change: attn+proj FUSED (k_attnp, 1 block=1 window,
//   4 waves). Phase1 = R24 attn (wave-private Pw/Vt, no barrier), O -> shared
//   O_lds[49][392] bf16. One __syncthreads. Phase2 = proj per wave (96 cols,
//   K=384 from O_lds; B-frags from L2-resident wp_bt), fp32 out.
//   Deletes proj dispatch + O round-trip (308MB). LDS 78.9KB -> 2 blk/CU.
//   qkv GEMM / cvt / bm / cvt_w = R24 verbatim.

typedef __attribute__((ext_vector_type(8))) short bf16x8;
typedef __attribute__((ext_vector_type(4))) float f32x4;

#define SEQ_N  49
#define CH     384
#define QKV_N  1152
#define UNIT_ROWS 3136   // 64 windows * 49 rows
#define BM2_ELEMS (64 * 12 * 49 * 64)   // 2,408,448 floats (9.6 MB)
#define OLDS_STRIDE 392  // els; 784B row -> 4-bank step -> 2-way (free)

__device__ __forceinline__ unsigned short f2b(float f) {
    union { float f; unsigned int u; } v; v.f = f;
    return (unsigned short)((v.u + 0x7FFFu + ((v.u >> 16) & 1u)) >> 16);
}

__device__ __forceinline__ bf16x8 ld8(const unsigned short* p) {
    return *(const bf16x8*)p;
}

// async global->LDS, 16B/lane; lds dst is wave-uniform base + lane*16
__device__ __forceinline__ void gload16(const unsigned short* g, unsigned short* l) {
    __builtin_amdgcn_global_load_lds(
        (const __attribute__((address_space(1))) unsigned int*)g,
        (__attribute__((address_space(3))) unsigned int*)l, 16, 0, 0);
}

// bijective XCD-chunking swizzle (m204)
__device__ __forceinline__ int xcd_swizzle(int orig, int T) {
    int q = T >> 3, r = T & 7;
    int xcd = orig & 7, idx = orig >> 3;
    return (xcd < r ? xcd * (q + 1) : r * (q + 1) + (xcd - r) * q) + idx;
}

// ---------------- weight convert+transpose: Bt[n][k] = bf16(W[k][n]) --------
__global__ __launch_bounds__(256) void k_cvt_w(const float* __restrict__ wq,
        const float* __restrict__ wp, unsigned short* __restrict__ oq,
        unsigned short* __restrict__ op)
{
    int t = blockIdx.x * 256 + threadIdx.x;
    if (t < QKV_N * CH) {
        int n = t / CH, k = t - n * CH;
        oq[t] = f2b(wq[(size_t)k * QKV_N + n]);
    }
    if (t < CH * CH) {
        int n = t / CH, k = t - n * CH;
        op[t] = f2b(wp[(size_t)k * CH + n]);
    }
}

// ---------------- fragment-ordered bias+mask: bm2[w][h][i][j15][nt] ----------
__global__ __launch_bounds__(256) void k_bm(const float* __restrict__ btab,
        const float* __restrict__ mask, float* __restrict__ bm2)
{
    int t = blockIdx.x * 256 + threadIdx.x;
    if (t >= BM2_ELEMS) return;
    int w    = t / (12 * 49 * 64);
    int rem  = t - w * 12 * 49 * 64;
    int h    = rem / (49 * 64);
    int rem2 = rem - h * 49 * 64;
    int i    = rem2 >> 6;
    int s    = rem2 & 63;
    int j15  = s >> 2, nt = s & 3;
    int j    = nt * 16 + j15;
    float v = -1e30f;
    if (j < 49) {
        int ih = i / 7, iw = i - (i / 7) * 7;
        int jh = j / 7, jw = j - (j / 7) * 7;
        int idx = (ih - jh + 6) * 13 + (iw - jw + 6);
        v = btab[idx * 12 + h] + mask[(size_t)w * 2401 + i * 49 + j];
    }
    bm2[t] = v;
}

// ---------------- x fp32 -> bf16 (vectorized, grid-stride) -------------------
__global__ __launch_bounds__(256) void k_cvt(const float* __restrict__ in,
        unsigned short* __restrict__ outp, int n8)
{
    int stride = gridDim.x * 256;
    for (int i = blockIdx.x * 256 + threadIdx.x; i < n8; i += stride) {
        const float4* p = (const float4*)(in + (size_t)i * 8);
        float4 a = p[0], b = p[1];
        uint4 v;
        v.x = (unsigned)f2b(a.x) | ((unsigned)f2b(a.y) << 16);
        v.y = (unsigned)f2b(a.z) | ((unsigned)f2b(a.w) << 16);
        v.z = (unsigned)f2b(b.x) | ((unsigned)f2b(b.y) << 16);
        v.w = (unsigned)f2b(b.z) | ((unsigned)f2b(b.w) << 16);
        *(uint4*)(outp + (size_t)i * 8) = v;
    }
}

// ---------------- 8-wave GEMM, 1 barrier/K-step: C = A @ Bt^T + bias ---------
// (qkv only now.) 128x128 tile, BK=32, 512 threads (8 waves, 64x32 each).
template<int OUTF32>
__global__ __launch_bounds__(512, 6) void k_gemm(
        const unsigned short* __restrict__ A, int lda,
        const unsigned short* __restrict__ Bt, int K,
        const float* __restrict__ bias,
        unsigned short* __restrict__ Cb, float* __restrict__ Cf, int ldc,
        int M, int ntiles, int mtiles)
{
    __shared__ unsigned short As[3 * 4096];
    __shared__ unsigned short Bs[3 * 4096];
    const int wg = xcd_swizzle(blockIdx.x, mtiles * ntiles);
    const int m0 = (wg / ntiles) * 128;
    const int n0 = (wg % ntiles) * 128;
    const int tid = threadIdx.x;
    const int lane = tid & 63, wv = tid >> 6;
    const int wr = wv >> 2, wc = wv & 3;
    const int l15 = lane & 15, g = lane >> 4;

    f32x4 acc[4][2];
#pragma unroll
    for (int a = 0; a < 4; ++a)
#pragma unroll
        for (int b = 0; b < 2; ++b) acc[a][b] = (f32x4){0.f, 0.f, 0.f, 0.f};

    int arow = m0 + (tid >> 2); if (arow > M - 1) arow = M - 1;
    const unsigned short* aP = A + (size_t)arow * lda + (tid & 3) * 8;
    const unsigned short* bP = Bt + (size_t)(n0 + (tid >> 2)) * K + (tid & 3) * 8;
    const int lo = wv * 512;

#define STAGE(kt, buf) do {                                \
        gload16(aP + (kt), &As[(buf) * 4096 + lo]);        \
        gload16(bP + (kt), &Bs[(buf) * 4096 + lo]);        \
    } while (0)

#define COMPUTE(buf) do {                                                       \
        bf16x8 af[4], bfr[2];                                                   \
        _Pragma("unroll")                                                       \
        for (int mt = 0; mt < 4; ++mt)                                          \
            af[mt] = ld8(&As[(buf) * 4096 + (wr * 64 + mt * 16 + l15) * 32 + g * 8]); \
        _Pragma("unroll")                                                       \
        for (int nt = 0; nt < 2; ++nt)                                          \
            bfr[nt] = ld8(&Bs[(buf) * 4096 + (wc * 32 + nt * 16 + l15) * 32 + g * 8]); \
        __builtin_amdgcn_s_setprio(1);                                          \
        _Pragma("unroll")                                                       \
        for (int mt = 0; mt < 4; ++mt)                                          \
            _Pragma("unroll")                                                   \
            for (int nt = 0; nt < 2; ++nt)                                      \
                acc[mt][nt] = __builtin_amdgcn_mfma_f32_16x16x32_bf16(          \
                        af[mt], bfr[nt], acc[mt][nt], 0, 0, 0);                 \
        __builtin_amdgcn_s_setprio(0);                                          \
    } while (0)

    const int nsteps = K >> 5;

    STAGE(0, 0);
    STAGE(32, 1);

    for (int t = 0; t < nsteps; ++t) {
        if (t + 1 < nsteps) asm volatile("s_waitcnt vmcnt(2)" ::: "memory");
        else                asm volatile("s_waitcnt vmcnt(0)" ::: "memory");
        __builtin_amdgcn_sched_barrier(0);
        __builtin_amdgcn_s_barrier();
        __builtin_amdgcn_sched_barrier(0);
        if (t + 2 < nsteps) {
            int pf = t + 2; pf -= (pf / 3) * 3;
            STAGE((t + 2) * 32, pf);
        }
        COMPUTE(t - (t / 3) * 3);
    }
#undef STAGE
#undef COMPUTE

#pragma unroll
    for (int mt = 0; mt < 4; ++mt)
#pragma unroll
        for (int nt = 0; nt < 2; ++nt) {
            int col = n0 + wc * 32 + nt * 16 + l15;
            float bb = bias[col];
#pragma unroll
            for (int r = 0; r < 4; ++r) {
                int row = m0 + wr * 64 + mt * 16 + g * 4 + r;
                if (row < M) {
                    if (OUTF32)
                        Cf[(size_t)row * ldc + col] = acc[mt][nt][r] + bb;
                    else
                        Cb[(size_t)row * ldc + col] = f2b(acc[mt][nt][r] + bb);
                }
            }
        }
}

// ---------------- fused attention + proj: 1 block = 1 window -----------------
// 4 waves; wave wv handles heads {wv, wv+4, wv+8} (phase 1, wave-private
// Pw/Vt, no barriers), O -> O_lds[49][392]. One barrier. Phase 2: wave wv
// computes out cols wv*96..+95 over K=384 (A from O_lds, B from wp_bt/L2).
__global__ __launch_bounds__(256) void k_attnp(
        const unsigned short* __restrict__ qkv,
        const float* __restrict__ bm2,
        const unsigned short* __restrict__ wp_bt,
        const float* __restrict__ proj_b,
        float* __restrict__ out, int win_base_rows)
{
    extern __shared__ unsigned short sm[];
    const int tid = threadIdx.x;
    const int lane = tid & 63, wv = tid >> 6;
    const int l15 = lane & 15, g = lane >> 4;
    const int winloc = blockIdx.x;
    const int wimg = winloc & 63;
    unsigned short* O_lds = sm;                          // [49][392]
    unsigned short* Vt = sm + SEQ_N * OLDS_STRIDE + wv * 5056;  // [32][72]
    unsigned short* Pw = Vt + 2304;                      // [49][56]
    const unsigned short* src = qkv + (size_t)winloc * SEQ_N * QKV_N;

    for (int hi = 0; hi < 3; ++hi) {
        const int h = wv + hi * 4;
        const int co = h * 32;
        const float* bm2h = bm2 + ((size_t)(wimg * 12 + h)) * (49 * 64);

        // ---- stage V^T (pad k>=48 zero)
        for (int t = lane; t < 32 * 16; t += 64) {
            int c = t >> 4, kk = 48 + (t & 15);
            Vt[c * 72 + kk] = 0;
        }
        for (int t = lane; t < 49 * 4; t += 64) {
            int row = t >> 2, cb = (t & 3) * 8;
            const unsigned short* vp = src + (size_t)row * QKV_N + 768 + co + cb;
            ushort4 a = ((const ushort4*)vp)[0];
            ushort4 b = ((const ushort4*)vp)[1];
            Vt[(cb + 0) * 72 + row] = a.x; Vt[(cb + 1) * 72 + row] = a.y;
            Vt[(cb + 2) * 72 + row] = a.z; Vt[(cb + 3) * 72 + row] = a.w;
            Vt[(cb + 4) * 72 + row] = b.x; Vt[(cb + 5) * 72 + row] = b.y;
            Vt[(cb + 6) * 72 + row] = b.z; Vt[(cb + 7) * 72 + row] = b.w;
        }

        bf16x8 qf[4], kf[4];
#pragma unroll
        for (int mt = 0; mt < 4; ++mt) {
            int r = mt * 16 + l15; if (r > 48) r = 48;
            qf[mt] = ld8(src + (size_t)r * QKV_N + co + g * 8);
        }
#pragma unroll
        for (int nt = 0; nt < 4; ++nt) {
            int r = nt * 16 + l15; if (r > 48) r = 48;
            kf[nt] = ld8(src + (size_t)r * QKV_N + CH + co + g * 8);
        }

        f32x4 sa[4][4];
#pragma unroll
        for (int mt = 0; mt < 4; ++mt)
#pragma unroll
            for (int nt = 0; nt < 4; ++nt) sa[mt][nt] = (f32x4){0.f, 0.f, 0.f, 0.f};
#pragma unroll
        for (int mt = 0; mt < 4; ++mt)
#pragma unroll
            for (int nt = 0; nt < 4; ++nt)
                sa[mt][nt] = __builtin_amdgcn_mfma_f32_16x16x32_bf16(
                        qf[mt], kf[nt], sa[mt][nt], 0, 0, 0);

        const float scale = 0.17677669529663687f;
#pragma unroll
        for (int mt = 0; mt < 4; ++mt) {
#pragma unroll
            for (int r = 0; r < 4; ++r) {
                int i = mt * 16 + g * 4 + r;
                int ic = i < 49 ? i : 48;
                float4 bv = *(const float4*)(bm2h + (size_t)ic * 64 + l15 * 4);
                float sv[4];
                sv[0] = sa[mt][0][r] * scale + bv.x;
                sv[1] = sa[mt][1][r] * scale + bv.y;
                sv[2] = sa[mt][2][r] * scale + bv.z;
                sv[3] = sa[mt][3][r] * scale + bv.w;
                float mx = fmaxf(fmaxf(sv[0], sv[1]), fmaxf(sv[2], sv[3]));
#pragma unroll
                for (int d = 1; d < 16; d <<= 1) mx = fmaxf(mx, __shfl_xor(mx, d));
                float sum = 0.f;
#pragma unroll
                for (int nt = 0; nt < 4; ++nt) { sv[nt] = __expf(sv[nt] - mx); sum += sv[nt]; }
#pragma unroll
                for (int d = 1; d < 16; d <<= 1) sum += __shfl_xor(sum, d);
                float inv = 1.0f / sum;
                if (i < 49) {
#pragma unroll
                    for (int nt = 0; nt < 4; ++nt) {
                        int j = nt * 16 + l15;
                        if (j < 56) Pw[i * 56 + j] = f2b(sv[nt] * inv);
                    }
                }
            }
        }
        // no barrier: Pw/Vt wave-private; per-wave DS ordering suffices

        f32x4 oa[4][2];
#pragma unroll
        for (int mt = 0; mt < 4; ++mt)
#pragma unroll
            for (int nt = 0; nt < 2; ++nt) oa[mt][nt] = (f32x4){0.f, 0.f, 0.f, 0.f};
#pragma unroll
        for (int ks = 0; ks < 2; ++ks) {
            bf16x8 pf[4];
#pragma unroll
            for (int mt = 0; mt < 4; ++mt) {
                int pr = mt * 16 + l15; if (pr > 48) pr = 48;
                pf[mt] = ld8(Pw + pr * 56 + ks * 32 + g * 8);   // overrun cols x0
            }
#pragma unroll
            for (int nt = 0; nt < 2; ++nt) {
                bf16x8 vf = ld8(Vt + (nt * 16 + l15) * 72 + ks * 32 + g * 8);
#pragma unroll
                for (int mt = 0; mt < 4; ++mt)
                    oa[mt][nt] = __builtin_amdgcn_mfma_f32_16x16x32_bf16(
                            pf[mt], vf, oa[mt][nt], 0, 0, 0);
            }
        }

        // ---- O_h -> O_lds cols co..co+31
#pragma unroll
        for (int mt = 0; mt < 4; ++mt)
#pragma unroll
            for (int r = 0; r < 4; ++r) {
                int i = mt * 16 + g * 4 + r;
                if (i < 49) {
#pragma unroll
                    for (int nt = 0; nt < 2; ++nt)
                        O_lds[i * OLDS_STRIDE + co + nt * 16 + l15] = f2b(oa[mt][nt][r]);
                }
            }
    }

    __syncthreads();   // all 12 heads' O visible block-wide

    // ---- phase 2: proj. Wave wv -> out cols wv*96 .. wv*96+95, K=384.
    f32x4 pacc[4][6];
#pragma unroll
    for (int a = 0; a < 4; ++a)
#pragma unroll
        for (int b = 0; b < 6; ++b) pacc[a][b] = (f32x4){0.f, 0.f, 0.f, 0.f};

    for (int ks = 0; ks < 12; ++ks) {
        bf16x8 paf[4];
#pragma unroll
        for (int mt = 0; mt < 4; ++mt) {
            int pr = mt * 16 + l15; if (pr > 48) pr = 48;
            paf[mt] = ld8(&O_lds[pr * OLDS_STRIDE + ks * 32 + g * 8]);
        }
#pragma unroll
        for (int nt = 0; nt < 6; ++nt) {
            bf16x8 pbf = ld8(wp_bt +
                (size_t)(wv * 96 + nt * 16 + l15) * CH + ks * 32 + g * 8);
#pragma unroll
            for (int mt = 0; mt < 4; ++mt)
                pacc[mt][nt] = __builtin_amdgcn_mfma_f32_16x16x32_bf16(
                        paf[mt], pbf, pacc[mt][nt], 0, 0, 0);
        }
    }

#pragma unroll
    for (int mt = 0; mt < 4; ++mt)
#pragma unroll
        for (int nt = 0; nt < 6; ++nt) {
            int col = wv * 96 + nt * 16 + l15;
            float bb = proj_b[col];
#pragma unroll
            for (int r = 0; r < 4; ++r) {
                int row = mt * 16 + g * 4 + r;
                if (row < SEQ_N)
                    out[(size_t)(win_base_rows + winloc * SEQ_N + row) * CH + col]
                        = pacc[mt][nt][r] + bb;
            }
        }
}

extern "C" void kernel_launch(void* const* d_in, const int* in_sizes, int n_in,
                              void* d_out, int out_size, void* d_ws, size_t ws_size,
                              hipStream_t stream) {
    const float* x      = (const float*)d_in[0];
    const float* mask   = (const float*)d_in[1];
    const float* qkv_w  = (const float*)d_in[2];
    const float* qkv_b  = (const float*)d_in[3];
    const float* proj_w = (const float*)d_in[4];
    const float* proj_b = (const float*)d_in[5];
    const float* btab   = (const float*)d_in[6];
    float* out = (float*)d_out;

    unsigned short* wq_bt = (unsigned short*)d_ws;
    unsigned short* wp_bt = wq_bt + QKV_N * CH;
    float*          bm2   = (float*)(wp_bt + CH * CH);
    unsigned short* base  = (unsigned short*)(bm2 + BM2_ELEMS);
    const size_t fixed = (size_t)(QKV_N * CH + CH * CH) * 2 + (size_t)BM2_ELEMS * 4;
    const size_t unit  = (size_t)UNIT_ROWS * (CH + QKV_N) * 2;
    if (ws_size < fixed + unit) return;
    int upc = (int)((ws_size - fixed) / unit);
    if (upc > 64) upc = 64;
    unsigned short* xb  = base;
    unsigned short* qkv = base + (size_t)upc * UNIT_ROWS * CH;

    const int smemA = (SEQ_N * OLDS_STRIDE + 4 * 5056) * 2;   // 78,864 B
    hipFuncSetAttribute(reinterpret_cast<const void*>(k_attnp),
                        hipFuncAttributeMaxDynamicSharedMemorySize, smemA);

    dim3 blk(256);
    k_cvt_w<<<dim3((QKV_N * CH + 255) / 256), blk, 0, stream>>>(qkv_w, proj_w, wq_bt, wp_bt);
    k_bm   <<<dim3((BM2_ELEMS + 255) / 256), blk, 0, stream>>>(btab, mask, bm2);

    for (int u0 = 0; u0 < 64; u0 += upc) {
        int units = (64 - u0) < upc ? (64 - u0) : upc;
        int m_base = u0 * UNIT_ROWS;
        int Mc = units * UNIT_ROWS;
        int mtiles = (Mc + 127) / 128;
        k_cvt<<<dim3(2048), blk, 0, stream>>>(x + (size_t)m_base * CH, xb, Mc * 48);
        k_gemm<0><<<dim3(mtiles * 9), dim3(512), 0, stream>>>(
                xb, CH, wq_bt, CH, qkv_b, qkv, nullptr, QKV_N, Mc, 9, mtiles);
        k_attnp<<<dim3(units * 64), blk, smemA, stream>>>(
                qkv, bm2, wp_bt, proj_b, out, m_base);
    }
}

// Round 26
// 859.242 us; speedup vs baseline: 1.5857x; 1.5857x over previous
//
#include <hip/hip_runtime.h>
#include <hip/hip_bf16.h>

// WindowAttention (Swin) on MI355X — round 26 (FINAL = R23, session best 859us)
//   Pipeline: k_cvt_w + k_bm (tables) -> k_cvt (x->bf16) -> k_gemm<0> (qkv,
//   128x128 BK32, 8 waves 64x32, 3-buf counted-vmcnt, 1 barrier/step)
//   -> k_attn (1 wave/(window,head), bm2 float4 bias+mask, no barrier)
//   -> k_gemm<1> (proj, fp32 out).
//   R24 (Pw shrink) and R25 (attn+proj fusion) were neutral/regression;
//   R23 is the best measured configuration.

typedef __attribute__((ext_vector_type(8))) short bf16x8;
typedef __attribute__((ext_vector_type(4))) float f32x4;

#define SEQ_N  49
#define CH     384
#define QKV_N  1152
#define UNIT_ROWS 3136   // 64 windows * 49 rows
#define BM2_ELEMS (64 * 12 * 49 * 64)   // 2,408,448 floats (9.6 MB)

__device__ __forceinline__ unsigned short f2b(float f) {
    union { float f; unsigned int u; } v; v.f = f;
    return (unsigned short)((v.u + 0x7FFFu + ((v.u >> 16) & 1u)) >> 16);
}

__device__ __forceinline__ bf16x8 ld8(const unsigned short* p) {
    return *(const bf16x8*)p;
}

// async global->LDS, 16B/lane; lds dst is wave-uniform base + lane*16
__device__ __forceinline__ void gload16(const unsigned short* g, unsigned short* l) {
    __builtin_amdgcn_global_load_lds(
        (const __attribute__((address_space(1))) unsigned int*)g,
        (__attribute__((address_space(3))) unsigned int*)l, 16, 0, 0);
}

// bijective XCD-chunking swizzle (m204)
__device__ __forceinline__ int xcd_swizzle(int orig, int T) {
    int q = T >> 3, r = T & 7;
    int xcd = orig & 7, idx = orig >> 3;
    return (xcd < r ? xcd * (q + 1) : r * (q + 1) + (xcd - r) * q) + idx;
}

// ---------------- weight convert+transpose: Bt[n][k] = bf16(W[k][n]) --------
__global__ __launch_bounds__(256) void k_cvt_w(const float* __restrict__ wq,
        const float* __restrict__ wp, unsigned short* __restrict__ oq,
        unsigned short* __restrict__ op)
{
    int t = blockIdx.x * 256 + threadIdx.x;
    if (t < QKV_N * CH) {
        int n = t / CH, k = t - n * CH;
        oq[t] = f2b(wq[(size_t)k * QKV_N + n]);
    }
    if (t < CH * CH) {
        int n = t / CH, k = t - n * CH;
        op[t] = f2b(wp[(size_t)k * CH + n]);
    }
}

// ---------------- fragment-ordered bias+mask: bm2[w][h][i][j15][nt] ----------
__global__ __launch_bounds__(256) void k_bm(const float* __restrict__ btab,
        const float* __restrict__ mask, float* __restrict__ bm2)
{
    int t = blockIdx.x * 256 + threadIdx.x;
    if (t >= BM2_ELEMS) return;
    int w    = t / (12 * 49 * 64);
    int rem  = t - w * 12 * 49 * 64;
    int h    = rem / (49 * 64);
    int rem2 = rem - h * 49 * 64;
    int i    = rem2 >> 6;
    int s    = rem2 & 63;
    int j15  = s >> 2, nt = s & 3;
    int j    = nt * 16 + j15;
    float v = -1e30f;
    if (j < 49) {
        int ih = i / 7, iw = i - (i / 7) * 7;
        int jh = j / 7, jw = j - (j / 7) * 7;
        int idx = (ih - jh + 6) * 13 + (iw - jw + 6);
        v = btab[idx * 12 + h] + mask[(size_t)w * 2401 + i * 49 + j];
    }
    bm2[t] = v;
}

// ---------------- x fp32 -> bf16 (vectorized, grid-stride) -------------------
__global__ __launch_bounds__(256) void k_cvt(const float* __restrict__ in,
        unsigned short* __restrict__ outp, int n8)
{
    int stride = gridDim.x * 256;
    for (int i = blockIdx.x * 256 + threadIdx.x; i < n8; i += stride) {
        const float4* p = (const float4*)(in + (size_t)i * 8);
        float4 a = p[0], b = p[1];
        uint4 v;
        v.x = (unsigned)f2b(a.x) | ((unsigned)f2b(a.y) << 16);
        v.y = (unsigned)f2b(a.z) | ((unsigned)f2b(a.w) << 16);
        v.z = (unsigned)f2b(b.x) | ((unsigned)f2b(b.y) << 16);
        v.w = (unsigned)f2b(b.z) | ((unsigned)f2b(b.w) << 16);
        *(uint4*)(outp + (size_t)i * 8) = v;
    }
}

// ---------------- 8-wave GEMM, 1 barrier/K-step: C = A @ Bt^T + bias ---------
// 128x128 tile, BK=32, 512 threads (8 waves, 64x32 each). 3-buf LDS,
// depth-2 prefetch. Loop: vmcnt(2) -> barrier -> STAGE(t+2) -> COMPUTE(t).
template<int OUTF32>
__global__ __launch_bounds__(512, 6) void k_gemm(
        const unsigned short* __restrict__ A, int lda,
        const unsigned short* __restrict__ Bt, int K,
        const float* __restrict__ bias,
        unsigned short* __restrict__ Cb, float* __restrict__ Cf, int ldc,
        int M, int ntiles, int mtiles)
{
    __shared__ unsigned short As[3 * 4096];
    __shared__ unsigned short Bs[3 * 4096];
    const int wg = xcd_swizzle(blockIdx.x, mtiles * ntiles);
    const int m0 = (wg / ntiles) * 128;
    const int n0 = (wg % ntiles) * 128;
    const int tid = threadIdx.x;
    const int lane = tid & 63, wv = tid >> 6;
    const int wr = wv >> 2, wc = wv & 3;
    const int l15 = lane & 15, g = lane >> 4;

    f32x4 acc[4][2];
#pragma unroll
    for (int a = 0; a < 4; ++a)
#pragma unroll
        for (int b = 0; b < 2; ++b) acc[a][b] = (f32x4){0.f, 0.f, 0.f, 0.f};

    int arow = m0 + (tid >> 2); if (arow > M - 1) arow = M - 1;
    const unsigned short* aP = A + (size_t)arow * lda + (tid & 3) * 8;
    const unsigned short* bP = Bt + (size_t)(n0 + (tid >> 2)) * K + (tid & 3) * 8;
    const int lo = wv * 512;

#define STAGE(kt, buf) do {                                \
        gload16(aP + (kt), &As[(buf) * 4096 + lo]);        \
        gload16(bP + (kt), &Bs[(buf) * 4096 + lo]);        \
    } while (0)

#define COMPUTE(buf) do {                                                       \
        bf16x8 af[4], bfr[2];                                                   \
        _Pragma("unroll")                                                       \
        for (int mt = 0; mt < 4; ++mt)                                          \
            af[mt] = ld8(&As[(buf) * 4096 + (wr * 64 + mt * 16 + l15) * 32 + g * 8]); \
        _Pragma("unroll")                                                       \
        for (int nt = 0; nt < 2; ++nt)                                          \
            bfr[nt] = ld8(&Bs[(buf) * 4096 + (wc * 32 + nt * 16 + l15) * 32 + g * 8]); \
        __builtin_amdgcn_s_setprio(1);                                          \
        _Pragma("unroll")                                                       \
        for (int mt = 0; mt < 4; ++mt)                                          \
            _Pragma("unroll")                                                   \
            for (int nt = 0; nt < 2; ++nt)                                      \
                acc[mt][nt] = __builtin_amdgcn_mfma_f32_16x16x32_bf16(          \
                        af[mt], bfr[nt], acc[mt][nt], 0, 0, 0);                 \
        __builtin_amdgcn_s_setprio(0);                                          \
    } while (0)

    const int nsteps = K >> 5;           // 12 (qkv) or 36 (proj)

    STAGE(0, 0);
    STAGE(32, 1);

    for (int t = 0; t < nsteps; ++t) {
        if (t + 1 < nsteps) asm volatile("s_waitcnt vmcnt(2)" ::: "memory");
        else                asm volatile("s_waitcnt vmcnt(0)" ::: "memory");
        __builtin_amdgcn_sched_barrier(0);
        __builtin_amdgcn_s_barrier();        // tile t ready; buf (t+2)%3 free
        __builtin_amdgcn_sched_barrier(0);
        if (t + 2 < nsteps) {
            int pf = t + 2; pf -= (pf / 3) * 3;
            STAGE((t + 2) * 32, pf);
        }
        COMPUTE(t - (t / 3) * 3);
    }
#undef STAGE
#undef COMPUTE

#pragma unroll
    for (int mt = 0; mt < 4; ++mt)
#pragma unroll
        for (int nt = 0; nt < 2; ++nt) {
            int col = n0 + wc * 32 + nt * 16 + l15;
            float bb = bias[col];
#pragma unroll
            for (int r = 0; r < 4; ++r) {
                int row = m0 + wr * 64 + mt * 16 + g * 4 + r;
                if (row < M) {
                    if (OUTF32)
                        Cf[(size_t)row * ldc + col] = acc[mt][nt][r] + bb;
                    else
                        Cb[(size_t)row * ldc + col] = f2b(acc[mt][nt][r] + bb);
                }
            }
        }
}

// ---------------- attention: 1 wave per (window, head), no barrier -----------
__global__ __launch_bounds__(256) void k_attn(unsigned short* __restrict__ qkv,
        const float* __restrict__ bm2)
{
    extern __shared__ unsigned short sm[];
    const int tid = threadIdx.x;
    const int lane = tid & 63, wv = tid >> 6;
    const int l15 = lane & 15, g = lane >> 4;
    const int pair = blockIdx.x * 4 + wv;
    const int winloc = pair / 12;
    const int h = pair - winloc * 12;
    const int wimg = winloc & 63;
    const int co = h * 32;
    unsigned short* Vt = sm + wv * 6048;     // [32][72]  V^T  (wave-private)
    unsigned short* Pw = Vt + 32 * 72;       // [52][72]  P    (wave-private)
    unsigned short* src = qkv + (size_t)winloc * SEQ_N * QKV_N;
    const float* bm2h = bm2 + ((size_t)(wimg * 12 + h)) * (49 * 64);

    for (int t = lane; t < 32 * 16; t += 64) {
        int c = t >> 4, kk = 48 + (t & 15);
        Vt[c * 72 + kk] = 0;
    }
    for (int t = lane; t < 49 * 4; t += 64) {
        int row = t >> 2, cb = (t & 3) * 8;
        const unsigned short* vp = src + (size_t)row * QKV_N + 768 + co + cb;
        ushort4 a = ((const ushort4*)vp)[0];
        ushort4 b = ((const ushort4*)vp)[1];
        Vt[(cb + 0) * 72 + row] = a.x; Vt[(cb + 1) * 72 + row] = a.y;
        Vt[(cb + 2) * 72 + row] = a.z; Vt[(cb + 3) * 72 + row] = a.w;
        Vt[(cb + 4) * 72 + row] = b.x; Vt[(cb + 5) * 72 + row] = b.y;
        Vt[(cb + 6) * 72 + row] = b.z; Vt[(cb + 7) * 72 + row] = b.w;
    }

    bf16x8 qf[4], kf[4];
#pragma unroll
    for (int mt = 0; mt < 4; ++mt) {
        int r = mt * 16 + l15; if (r > 48) r = 48;
        qf[mt] = ld8(src + (size_t)r * QKV_N + co + g * 8);
    }
#pragma unroll
    for (int nt = 0; nt < 4; ++nt) {
        int r = nt * 16 + l15; if (r > 48) r = 48;
        kf[nt] = ld8(src + (size_t)r * QKV_N + CH + co + g * 8);
    }

    f32x4 sa[4][4];
#pragma unroll
    for (int mt = 0; mt < 4; ++mt)
#pragma unroll
        for (int nt = 0; nt < 4; ++nt) sa[mt][nt] = (f32x4){0.f, 0.f, 0.f, 0.f};
#pragma unroll
    for (int mt = 0; mt < 4; ++mt)
#pragma unroll
        for (int nt = 0; nt < 4; ++nt)
            sa[mt][nt] = __builtin_amdgcn_mfma_f32_16x16x32_bf16(
                    qf[mt], kf[nt], sa[mt][nt], 0, 0, 0);

    const float scale = 0.17677669529663687f;
#pragma unroll
    for (int mt = 0; mt < 4; ++mt) {
#pragma unroll
        for (int r = 0; r < 4; ++r) {
            int i = mt * 16 + g * 4 + r;
            int ic = i < 49 ? i : 48;
            float4 bv = *(const float4*)(bm2h + (size_t)ic * 64 + l15 * 4);
            float sv[4];
            sv[0] = sa[mt][0][r] * scale + bv.x;
            sv[1] = sa[mt][1][r] * scale + bv.y;
            sv[2] = sa[mt][2][r] * scale + bv.z;
            sv[3] = sa[mt][3][r] * scale + bv.w;
            float mx = fmaxf(fmaxf(sv[0], sv[1]), fmaxf(sv[2], sv[3]));
#pragma unroll
            for (int d = 1; d < 16; d <<= 1) mx = fmaxf(mx, __shfl_xor(mx, d));
            float sum = 0.f;
#pragma unroll
            for (int nt = 0; nt < 4; ++nt) { sv[nt] = __expf(sv[nt] - mx); sum += sv[nt]; }
#pragma unroll
            for (int d = 1; d < 16; d <<= 1) sum += __shfl_xor(sum, d);
            float inv = 1.0f / sum;
            if (i < 52) {
#pragma unroll
                for (int nt = 0; nt < 4; ++nt)
                    Pw[i * 72 + nt * 16 + l15] = f2b(sv[nt] * inv);
            }
        }
    }
    // no __syncthreads — Pw/Vt are wave-private; per-wave DS ordering suffices

    f32x4 oa[4][2];
#pragma unroll
    for (int mt = 0; mt < 4; ++mt)
#pragma unroll
        for (int nt = 0; nt < 2; ++nt) oa[mt][nt] = (f32x4){0.f, 0.f, 0.f, 0.f};
#pragma unroll
    for (int ks = 0; ks < 2; ++ks) {
        bf16x8 pf[4];
#pragma unroll
        for (int mt = 0; mt < 4; ++mt) {
            int pr = mt * 16 + l15; if (pr > 51) pr = 51;
            pf[mt] = ld8(Pw + pr * 72 + ks * 32 + g * 8);
        }
#pragma unroll
        for (int nt = 0; nt < 2; ++nt) {
            bf16x8 vf = ld8(Vt + (nt * 16 + l15) * 72 + ks * 32 + g * 8);
#pragma unroll
            for (int mt = 0; mt < 4; ++mt)
                oa[mt][nt] = __builtin_amdgcn_mfma_f32_16x16x32_bf16(
                        pf[mt], vf, oa[mt][nt], 0, 0, 0);
        }
    }

#pragma unroll
    for (int mt = 0; mt < 4; ++mt)
#pragma unroll
        for (int r = 0; r < 4; ++r) {
            int i = mt * 16 + g * 4 + r;
            if (i < 49) {
#pragma unroll
                for (int nt = 0; nt < 2; ++nt)
                    src[(size_t)i * QKV_N + co + nt * 16 + l15] = f2b(oa[mt][nt][r]);
            }
        }
}

extern "C" void kernel_launch(void* const* d_in, const int* in_sizes, int n_in,
                              void* d_out, int out_size, void* d_ws, size_t ws_size,
                              hipStream_t stream) {
    const float* x      = (const float*)d_in[0];
    const float* mask   = (const float*)d_in[1];
    const float* qkv_w  = (const float*)d_in[2];
    const float* qkv_b  = (const float*)d_in[3];
    const float* proj_w = (const float*)d_in[4];
    const float* proj_b = (const float*)d_in[5];
    const float* btab   = (const float*)d_in[6];
    float* out = (float*)d_out;

    unsigned short* wq_bt = (unsigned short*)d_ws;
    unsigned short* wp_bt = wq_bt + QKV_N * CH;
    float*          bm2   = (float*)(wp_bt + CH * CH);
    unsigned short* base  = (unsigned short*)(bm2 + BM2_ELEMS);
    const size_t fixed = (size_t)(QKV_N * CH + CH * CH) * 2 + (size_t)BM2_ELEMS * 4;
    const size_t unit  = (size_t)UNIT_ROWS * (CH + QKV_N) * 2;
    if (ws_size < fixed + unit) return;
    int upc = (int)((ws_size - fixed) / unit);
    if (upc > 64) upc = 64;
    unsigned short* xb  = base;
    unsigned short* qkv = base + (size_t)upc * UNIT_ROWS * CH;

    const int smem2 = 4 * 6048 * 2;   // 48,384 B -> 3 blocks/CU (attn)
    hipFuncSetAttribute(reinterpret_cast<const void*>(k_attn),
                        hipFuncAttributeMaxDynamicSharedMemorySize, smem2);

    dim3 blk(256);
    k_cvt_w<<<dim3((QKV_N * CH + 255) / 256), blk, 0, stream>>>(qkv_w, proj_w, wq_bt, wp_bt);
    k_bm   <<<dim3((BM2_ELEMS + 255) / 256), blk, 0, stream>>>(btab, mask, bm2);

    for (int u0 = 0; u0 < 64; u0 += upc) {
        int units = (64 - u0) < upc ? (64 - u0) : upc;
        int m_base = u0 * UNIT_ROWS;
        int Mc = units * UNIT_ROWS;
        int mtiles = (Mc + 127) / 128;
        k_cvt<<<dim3(2048), blk, 0, stream>>>(x + (size_t)m_base * CH, xb, Mc * 48);
        k_gemm<0><<<dim3(mtiles * 9), dim3(512), 0, stream>>>(
                xb, CH, wq_bt, CH, qkv_b, qkv, nullptr, QKV_N, Mc, 9, mtiles);
        k_attn<<<dim3(units * 192), blk, smem2, stream>>>(qkv, bm2);
        k_gemm<1><<<dim3(mtiles * 3), dim3(512), 0, stream>>>(
                qkv, QKV_N, wp_bt, CH, proj_b, nullptr, out + (size_t)m_base * CH,
                CH, Mc, 3, mtiles);
    }
}